// Round 6
// baseline (1004.270 us; speedup 1.0000x reference)
//
#include <hip/hip_runtime.h>
#include <hip/hip_fp16.h>

// NoPropCTMomentNet: 10-step Euler of a 17->64->64->32->8 swish MLP, B=2M rows.
// Round 6: LDS eliminated. D->B layout transposes done in-register with
// v_permlane32_swap / v_permlane16_swap (motion is only among lanes
// {n,n+16,n+32,n+48} = lane bits 4/5; full permutation = 3-cycle
// (dataMid -> lane5 -> lane4 -> dataMid) = 4x swap32 then 4x swap16).
// t-column and b1 folded into W1 rows 16/17 (constant-1 input slot).
// No LDS, no barriers, no lgkm waits, no bank conflicts.

typedef __attribute__((ext_vector_type(8))) _Float16 half8;
typedef __attribute__((ext_vector_type(4))) float f32x4;

constexpr int NSTEP = 10;
constexpr float DT = 0.1f;
constexpr float LOG2E = 1.44269504f;
constexpr float LN2   = 0.69314718f;

__device__ __forceinline__ unsigned packh(float a, float b) {
    __half2 h = __floats2half2_rn(a, b);
    unsigned r; __builtin_memcpy(&r, &h, 4); return r;
}
__device__ __forceinline__ unsigned pkrtz(float a, float b) {
    auto z = __builtin_amdgcn_cvt_pkrtz(a, b);
    unsigned r; __builtin_memcpy(&r, &z, 4); return r;
}
__device__ __forceinline__ half8 mk8h(unsigned w0, unsigned w1,
                                      unsigned w2, unsigned w3) {
    union { unsigned w[4]; half8 h; } u;
    u.w[0] = w0; u.w[1] = w1; u.w[2] = w2; u.w[3] = w3;
    return u.h;
}

// exchange lane-bit5 <-> data-bit indexing {a,b}
__device__ __forceinline__ void plswap32(unsigned& a, unsigned& b) {
    auto r = __builtin_amdgcn_permlane32_swap(a, b, false, false);
    a = r[0]; b = r[1];
}
// exchange lane-bit4 <-> data-bit indexing {a,b}
__device__ __forceinline__ void plswap16(unsigned& a, unsigned& b) {
    auto r = __builtin_amdgcn_permlane16_swap(a, b, false, false);
    a = r[0]; b = r[1];
}
// value of x from the lane with bit4 flipped (valid at bit4==0 lanes)
__device__ __forceinline__ unsigned partner16(unsigned x) {
    unsigned a = x, b = x;
    plswap16(a, b);
    return b;   // b[bit4==0 lanes] = partner's x
}

// packed swish in scaled domain: 2 f32 preacts (z = log2e * true preact) ->
// u32 of 2 f16:  h^ = 0.5 z + |z| * q(2^-|z|),  q(e) ~ 1/(1+e) - 0.5
__device__ __forceinline__ unsigned swish2(float za, float zb) {
    auto zc = __builtin_amdgcn_cvt_pkrtz(za, zb);
    __half2 z; __builtin_memcpy(&z, &zc, 4);
    __half2 az = __habs2(z);
    __half2 e  = h2exp2(__hneg2(az));
    const __half2 C0 = __float2half2_rn( 0.5f);
    const __half2 C1 = __float2half2_rn(-0.996622f);
    const __half2 C2 = __float2half2_rn( 0.956088f);
    const __half2 C3 = __float2half2_rn(-0.777792f);
    const __half2 C4 = __float2half2_rn( 0.426000f);
    const __half2 C5 = __float2half2_rn(-0.107654f);
    __half2 q = __hfma2(e, __hfma2(e, __hfma2(e, __hfma2(e, __hfma2(e, C5, C4), C3), C2), C1), C0);
    __half2 hh = __hfma2(az, q, __hmul2(z, C0));
    unsigned r; __builtin_memcpy(&r, &hh, 4);
    return r;
}

// D(8 packed words, idx = 2c + b) -> B(two K=32 splits), in-register.
__device__ __forceinline__ void xpose64(unsigned w[8]) {
    plswap32(w[0], w[2]); plswap32(w[1], w[3]);
    plswap32(w[4], w[6]); plswap32(w[5], w[7]);
    plswap16(w[0], w[2]); plswap16(w[1], w[3]);
    plswap16(w[4], w[6]); plswap16(w[5], w[7]);
}
__device__ __forceinline__ void xpose32(unsigned w[4]) {
    plswap32(w[0], w[2]); plswap32(w[1], w[3]);
    plswap16(w[0], w[2]); plswap16(w[1], w[3]);
}

// A-fragment of W^T (chunk c, k-split s), fp16, scaled.
template <int NOUT, int KLIM, bool M8>
__device__ __forceinline__ half8 wfragh(const float* __restrict__ W, float scale,
                                        int c, int s, int n, int hi) {
    unsigned w[4];
#pragma unroll
    for (int p = 0; p < 4; ++p) {
        const int k0 = 32 * s + 8 * hi + 2 * p;
        const bool mok = !M8 || (n < 8);
        float a = (mok && (k0     < KLIM)) ? W[(size_t)k0 * NOUT + 16 * c + n] * scale : 0.0f;
        float b = (mok && (k0 + 1 < KLIM)) ? W[(size_t)(k0 + 1) * NOUT + 16 * c + n] * scale : 0.0f;
        w[p] = packh(a, b);
    }
    return mk8h(w[0], w[1], w[2], w[3]);
}

// W1 fragment with t-coeff at k=16 and bias at k=17 (virtual rows), scaled.
__device__ __forceinline__ half8 w1fragh(const float* __restrict__ W1,
                                         const float* __restrict__ b1,
                                         int c, int n, int hi) {
    unsigned w[4];
#pragma unroll
    for (int p = 0; p < 4; ++p) {
        const int k0 = 8 * hi + 2 * p;
        float a = (k0 < 17) ? W1[(size_t)k0 * 64 + 16 * c + n] * LOG2E
                            : (k0 == 17 ? b1[16 * c + n] * LOG2E : 0.0f);
        const int k1 = k0 + 1;
        float b = (k1 < 17) ? W1[(size_t)k1 * 64 + 16 * c + n] * LOG2E
                            : (k1 == 17 ? b1[16 * c + n] * LOG2E : 0.0f);
        w[p] = packh(a, b);
    }
    return mk8h(w[0], w[1], w[2], w[3]);
}

__device__ __forceinline__ f32x4 ldb4s(const float* p, float s) {
    f32x4 v = *(const f32x4*)p;
    v.x *= s; v.y *= s; v.z *= s; v.w *= s;
    return v;
}

__global__ __launch_bounds__(256) void noprop_mfma_kernel(
    const float* __restrict__ eta,
    const float* __restrict__ W1, const float* __restrict__ b1,
    const float* __restrict__ W2, const float* __restrict__ b2,
    const float* __restrict__ W3, const float* __restrict__ b3,
    const float* __restrict__ W4, const float* __restrict__ b4,
    float* __restrict__ out, int batch)
{
    const int lane = threadIdx.x & 63;
    const int n  = lane & 15;   // batch row within tile
    const int hi = lane >> 4;   // k-block (A/B) or m-block (C/D)

    // ---- persistent weight fragments (scaled domain)
    half8 W1f[4], W2f[4][2], W3f[2][2], W4f;
#pragma unroll
    for (int c = 0; c < 4; ++c) W1f[c] = w1fragh(W1, b1, c, n, hi);
#pragma unroll
    for (int c = 0; c < 4; ++c)
#pragma unroll
        for (int s = 0; s < 2; ++s) W2f[c][s] = wfragh<64, 64, false>(W2, 1.0f, c, s, n, hi);
#pragma unroll
    for (int c = 0; c < 2; ++c)
#pragma unroll
        for (int s = 0; s < 2; ++s) W3f[c][s] = wfragh<32, 64, false>(W3, 1.0f, c, s, n, hi);
    W4f = wfragh<8, 32, true>(W4, LN2, 0, 0, n, hi);

    // ---- bias fragments (C layout), b2/b3 scaled by log2e; b1 folded into W1
    f32x4 zero4 = {0.f, 0.f, 0.f, 0.f};
    f32x4 B2b[4], B3b[2], B4b;
#pragma unroll
    for (int c = 0; c < 4; ++c) B2b[c] = ldb4s(b2 + 16 * c + 4 * hi, LOG2E);
#pragma unroll
    for (int c = 0; c < 2; ++c) B3b[c] = ldb4s(b3 + 16 * c + 4 * hi, LOG2E);
    B4b = (hi < 2) ? *(const f32x4*)(b4 + 4 * hi) : zero4;

    const int nTiles = batch >> 4;
    const int gwave  = (int)((blockIdx.x * blockDim.x + threadIdx.x) >> 6);
    const int nWaves = (int)((gridDim.x * blockDim.x) >> 6);

    for (int tile = gwave; tile < nTiles; tile += nWaves) {
        const int row = (tile << 4) + n;
        const float* erow = eta + (size_t)row * 8;

        f32x4 e0 = *(const f32x4*)(erow);
        f32x4 e1 = *(const f32x4*)(erow + 4);

        // state D-frag: lane(hi<2) holds st[4hi+r] of row n, fp32 always
        f32x4 stD = zero4;
        if (hi == 0) stD = e0;
        if (hi == 1) stD = e1;

        const unsigned eP0 = pkrtz(e0.x, e0.y), eP1 = pkrtz(e0.z, e0.w);
        const unsigned eP2 = pkrtz(e1.x, e1.y), eP3 = pkrtz(e1.z, e1.w);

#pragma unroll 1
        for (int step = 0; step < NSTEP; ++step) {
            const float t = DT * (float)step;
            const unsigned tw = pkrtz(t, 1.0f);   // (t, 1) -> W1 rows 16,17

            // ---- build layer-1 B fragment in-register
            const unsigned pa = pkrtz(stD.x, stD.y);
            const unsigned pb = pkrtz(stD.z, stD.w);
            const unsigned paP = partner16(pa);   // partner's st pair (valid at bit4==0)
            const unsigned pbP = partner16(pb);
            unsigned b0 = (hi == 0) ? pa  : (hi == 1) ? eP0 : (hi == 2) ? tw : 0u;
            unsigned b1w = (hi == 0) ? pb  : (hi == 1) ? eP1 : 0u;
            unsigned b2w = (hi == 0) ? paP : (hi == 1) ? eP2 : 0u;
            unsigned b3w = (hi == 0) ? pbP : (hi == 1) ? eP3 : 0u;
            half8 Bx = mk8h(b0, b1w, b2w, b3w);

            // ---- layer 1 (17(+t,+1) -> 64)
            f32x4 a1[4];
#pragma unroll
            for (int c = 0; c < 4; ++c)
                a1[c] = __builtin_amdgcn_mfma_f32_16x16x32_f16(W1f[c], Bx, zero4, 0, 0, 0);
            unsigned w1w[8];
#pragma unroll
            for (int c = 0; c < 4; ++c) {
                w1w[2 * c]     = swish2(a1[c].x, a1[c].y);
                w1w[2 * c + 1] = swish2(a1[c].z, a1[c].w);
            }
            xpose64(w1w);
            half8 h1f0 = mk8h(w1w[0], w1w[1], w1w[2], w1w[3]);
            half8 h1f1 = mk8h(w1w[4], w1w[5], w1w[6], w1w[7]);

            // ---- layer 2 (64 -> 64)
            f32x4 a2[4];
#pragma unroll
            for (int c = 0; c < 4; ++c) {
                f32x4 t0 = __builtin_amdgcn_mfma_f32_16x16x32_f16(W2f[c][0], h1f0, B2b[c], 0, 0, 0);
                a2[c]    = __builtin_amdgcn_mfma_f32_16x16x32_f16(W2f[c][1], h1f1, t0, 0, 0, 0);
            }
            unsigned w2w[8];
#pragma unroll
            for (int c = 0; c < 4; ++c) {
                w2w[2 * c]     = swish2(a2[c].x, a2[c].y);
                w2w[2 * c + 1] = swish2(a2[c].z, a2[c].w);
            }
            xpose64(w2w);
            half8 h2f0 = mk8h(w2w[0], w2w[1], w2w[2], w2w[3]);
            half8 h2f1 = mk8h(w2w[4], w2w[5], w2w[6], w2w[7]);

            // ---- layer 3 (64 -> 32)
            f32x4 a3[2];
#pragma unroll
            for (int c = 0; c < 2; ++c) {
                f32x4 t0 = __builtin_amdgcn_mfma_f32_16x16x32_f16(W3f[c][0], h2f0, B3b[c], 0, 0, 0);
                a3[c]    = __builtin_amdgcn_mfma_f32_16x16x32_f16(W3f[c][1], h2f1, t0, 0, 0, 0);
            }
            unsigned w3w[4];
#pragma unroll
            for (int c = 0; c < 2; ++c) {
                w3w[2 * c]     = swish2(a3[c].x, a3[c].y);
                w3w[2 * c + 1] = swish2(a3[c].z, a3[c].w);
            }
            xpose32(w3w);
            half8 h3f = mk8h(w3w[0], w3w[1], w3w[2], w3w[3]);

            // ---- layer 4 (32 -> 8, true domain) + Euler update (fp32)
            f32x4 a4 = __builtin_amdgcn_mfma_f32_16x16x32_f16(W4f, h3f, B4b, 0, 0, 0);
            stD.x = fmaf(DT, a4.x, stD.x);
            stD.y = fmaf(DT, a4.y, stD.y);
            stD.z = fmaf(DT, a4.z, stD.z);
            stD.w = fmaf(DT, a4.w, stD.w);
        }

        if (hi < 2) *(f32x4*)(out + (size_t)row * 8 + 4 * hi) = stD;
    }
}

extern "C" void kernel_launch(void* const* d_in, const int* in_sizes, int n_in,
                              void* d_out, int out_size, void* d_ws, size_t ws_size,
                              hipStream_t stream) {
    const float* eta = (const float*)d_in[0];
    const float* W1  = (const float*)d_in[1];
    const float* b1  = (const float*)d_in[2];
    const float* W2  = (const float*)d_in[3];
    const float* b2  = (const float*)d_in[4];
    const float* W3  = (const float*)d_in[5];
    const float* b3  = (const float*)d_in[6];
    const float* W4  = (const float*)d_in[7];
    const float* b4  = (const float*)d_in[8];
    float* out = (float*)d_out;

    const int batch = in_sizes[0] / 8;
    const int block = 256;   // 4 waves
    const int grid  = 2048;  // 8192 waves -> 16 tiles/wave
    hipLaunchKernelGGL(noprop_mfma_kernel, dim3(grid), dim3(block), 0, stream,
                       eta, W1, b1, W2, b2, W3, b3, W4, b4, out, batch);
}

// Round 7
// 987.550 us; speedup vs baseline: 1.0169x; 1.0169x over previous
//
#include <hip/hip_runtime.h>
#include <hip/hip_fp16.h>

// NoPropCTMomentNet: 10-step Euler of a 17->64->64->32->8 swish MLP, B=2M rows.
// Round 7: R6 + TWO independent 16-row tiles per wave, interleaved through the
// whole step body (ILP x2). Discriminates latency-bound vs VALU-issue-bound.
// All transposes in-register (permlane16/32_swap); no LDS, no barriers.

typedef __attribute__((ext_vector_type(8))) _Float16 half8;
typedef __attribute__((ext_vector_type(4))) float f32x4;

constexpr int NSTEP = 10;
constexpr float DT = 0.1f;
constexpr float LOG2E = 1.44269504f;
constexpr float LN2   = 0.69314718f;

__device__ __forceinline__ unsigned packh(float a, float b) {
    __half2 h = __floats2half2_rn(a, b);
    unsigned r; __builtin_memcpy(&r, &h, 4); return r;
}
__device__ __forceinline__ unsigned pkrtz(float a, float b) {
    auto z = __builtin_amdgcn_cvt_pkrtz(a, b);
    unsigned r; __builtin_memcpy(&r, &z, 4); return r;
}
__device__ __forceinline__ half8 mk8h(unsigned w0, unsigned w1,
                                      unsigned w2, unsigned w3) {
    union { unsigned w[4]; half8 h; } u;
    u.w[0] = w0; u.w[1] = w1; u.w[2] = w2; u.w[3] = w3;
    return u.h;
}

__device__ __forceinline__ void plswap32(unsigned& a, unsigned& b) {
    auto r = __builtin_amdgcn_permlane32_swap(a, b, false, false);
    a = r[0]; b = r[1];
}
__device__ __forceinline__ void plswap16(unsigned& a, unsigned& b) {
    auto r = __builtin_amdgcn_permlane16_swap(a, b, false, false);
    a = r[0]; b = r[1];
}
__device__ __forceinline__ unsigned partner16(unsigned x) {
    unsigned a = x, b = x;
    plswap16(a, b);
    return b;
}

// packed swish in scaled domain: 2 f32 preacts (z = log2e * true preact) ->
// u32 of 2 f16:  h^ = 0.5 z + |z| * q(2^-|z|),  q(e) ~ 1/(1+e) - 0.5
__device__ __forceinline__ unsigned swish2(float za, float zb) {
    auto zc = __builtin_amdgcn_cvt_pkrtz(za, zb);
    __half2 z; __builtin_memcpy(&z, &zc, 4);
    __half2 az = __habs2(z);
    __half2 e  = h2exp2(__hneg2(az));
    const __half2 C0 = __float2half2_rn( 0.5f);
    const __half2 C1 = __float2half2_rn(-0.996622f);
    const __half2 C2 = __float2half2_rn( 0.956088f);
    const __half2 C3 = __float2half2_rn(-0.777792f);
    const __half2 C4 = __float2half2_rn( 0.426000f);
    const __half2 C5 = __float2half2_rn(-0.107654f);
    __half2 q = __hfma2(e, __hfma2(e, __hfma2(e, __hfma2(e, __hfma2(e, C5, C4), C3), C2), C1), C0);
    __half2 hh = __hfma2(az, q, __hmul2(z, C0));
    unsigned r; __builtin_memcpy(&r, &hh, 4);
    return r;
}

__device__ __forceinline__ void xpose64(unsigned w[8]) {
    plswap32(w[0], w[2]); plswap32(w[1], w[3]);
    plswap32(w[4], w[6]); plswap32(w[5], w[7]);
    plswap16(w[0], w[2]); plswap16(w[1], w[3]);
    plswap16(w[4], w[6]); plswap16(w[5], w[7]);
}
__device__ __forceinline__ void xpose32(unsigned w[4]) {
    plswap32(w[0], w[2]); plswap32(w[1], w[3]);
    plswap16(w[0], w[2]); plswap16(w[1], w[3]);
}

template <int NOUT, int KLIM, bool M8>
__device__ __forceinline__ half8 wfragh(const float* __restrict__ W, float scale,
                                        int c, int s, int n, int hi) {
    unsigned w[4];
#pragma unroll
    for (int p = 0; p < 4; ++p) {
        const int k0 = 32 * s + 8 * hi + 2 * p;
        const bool mok = !M8 || (n < 8);
        float a = (mok && (k0     < KLIM)) ? W[(size_t)k0 * NOUT + 16 * c + n] * scale : 0.0f;
        float b = (mok && (k0 + 1 < KLIM)) ? W[(size_t)(k0 + 1) * NOUT + 16 * c + n] * scale : 0.0f;
        w[p] = packh(a, b);
    }
    return mk8h(w[0], w[1], w[2], w[3]);
}

// W1 fragment with t-coeff at k=16 and bias at k=17 (virtual rows), scaled.
__device__ __forceinline__ half8 w1fragh(const float* __restrict__ W1,
                                         const float* __restrict__ b1,
                                         int c, int n, int hi) {
    unsigned w[4];
#pragma unroll
    for (int p = 0; p < 4; ++p) {
        const int k0 = 8 * hi + 2 * p;
        float a = (k0 < 17) ? W1[(size_t)k0 * 64 + 16 * c + n] * LOG2E
                            : (k0 == 17 ? b1[16 * c + n] * LOG2E : 0.0f);
        const int k1 = k0 + 1;
        float b = (k1 < 17) ? W1[(size_t)k1 * 64 + 16 * c + n] * LOG2E
                            : (k1 == 17 ? b1[16 * c + n] * LOG2E : 0.0f);
        w[p] = packh(a, b);
    }
    return mk8h(w[0], w[1], w[2], w[3]);
}

__device__ __forceinline__ f32x4 ldb4s(const float* p, float s) {
    f32x4 v = *(const f32x4*)p;
    v.x *= s; v.y *= s; v.z *= s; v.w *= s;
    return v;
}

__global__ __launch_bounds__(256) void noprop_mfma_kernel(
    const float* __restrict__ eta,
    const float* __restrict__ W1, const float* __restrict__ b1,
    const float* __restrict__ W2, const float* __restrict__ b2,
    const float* __restrict__ W3, const float* __restrict__ b3,
    const float* __restrict__ W4, const float* __restrict__ b4,
    float* __restrict__ out, int batch)
{
    const int lane = threadIdx.x & 63;
    const int n  = lane & 15;
    const int hi = lane >> 4;

    // ---- persistent weight fragments (scaled domain), shared by both tiles
    half8 W1f[4], W2f[4][2], W3f[2][2], W4f;
#pragma unroll
    for (int c = 0; c < 4; ++c) W1f[c] = w1fragh(W1, b1, c, n, hi);
#pragma unroll
    for (int c = 0; c < 4; ++c)
#pragma unroll
        for (int s = 0; s < 2; ++s) W2f[c][s] = wfragh<64, 64, false>(W2, 1.0f, c, s, n, hi);
#pragma unroll
    for (int c = 0; c < 2; ++c)
#pragma unroll
        for (int s = 0; s < 2; ++s) W3f[c][s] = wfragh<32, 64, false>(W3, 1.0f, c, s, n, hi);
    W4f = wfragh<8, 32, true>(W4, LN2, 0, 0, n, hi);

    f32x4 zero4 = {0.f, 0.f, 0.f, 0.f};
    f32x4 B2b[4], B3b[2], B4b;
#pragma unroll
    for (int c = 0; c < 4; ++c) B2b[c] = ldb4s(b2 + 16 * c + 4 * hi, LOG2E);
#pragma unroll
    for (int c = 0; c < 2; ++c) B3b[c] = ldb4s(b3 + 16 * c + 4 * hi, LOG2E);
    B4b = (hi < 2) ? *(const f32x4*)(b4 + 4 * hi) : zero4;

    const int nPairs = batch >> 5;                     // two 16-row tiles per pair
    const int gwave  = (int)((blockIdx.x * blockDim.x + threadIdx.x) >> 6);
    const int nWaves = (int)((gridDim.x * blockDim.x) >> 6);

    for (int pr = gwave; pr < nPairs; pr += nWaves) {
        int rows[2];
        rows[0] = (pr << 5) + n;          // tile A: rows pr*32 .. +15
        rows[1] = (pr << 5) + 16 + n;     // tile B: rows pr*32+16 .. +31

        f32x4 stD[2];
        unsigned eP[2][4];
#pragma unroll
        for (int u = 0; u < 2; ++u) {
            const float* erow = eta + (size_t)rows[u] * 8;
            f32x4 e0 = *(const f32x4*)(erow);
            f32x4 e1 = *(const f32x4*)(erow + 4);
            stD[u] = zero4;
            if (hi == 0) stD[u] = e0;
            if (hi == 1) stD[u] = e1;
            eP[u][0] = pkrtz(e0.x, e0.y); eP[u][1] = pkrtz(e0.z, e0.w);
            eP[u][2] = pkrtz(e1.x, e1.y); eP[u][3] = pkrtz(e1.z, e1.w);
        }

#pragma unroll 1
        for (int step = 0; step < NSTEP; ++step) {
            const float t = DT * (float)step;
            const unsigned tw = pkrtz(t, 1.0f);

            // ---- layer-1 B fragments (both tiles)
            half8 Bx[2];
#pragma unroll
            for (int u = 0; u < 2; ++u) {
                const unsigned pa = pkrtz(stD[u].x, stD[u].y);
                const unsigned pb = pkrtz(stD[u].z, stD[u].w);
                const unsigned paP = partner16(pa);
                const unsigned pbP = partner16(pb);
                unsigned b0 = (hi == 0) ? pa  : (hi == 1) ? eP[u][0] : (hi == 2) ? tw : 0u;
                unsigned w1 = (hi == 0) ? pb  : (hi == 1) ? eP[u][1] : 0u;
                unsigned w2 = (hi == 0) ? paP : (hi == 1) ? eP[u][2] : 0u;
                unsigned w3 = (hi == 0) ? pbP : (hi == 1) ? eP[u][3] : 0u;
                Bx[u] = mk8h(b0, w1, w2, w3);
            }

            // ---- layer 1 (17(+t,+1) -> 64)
            f32x4 a1[2][4];
#pragma unroll
            for (int u = 0; u < 2; ++u)
#pragma unroll
                for (int c = 0; c < 4; ++c)
                    a1[u][c] = __builtin_amdgcn_mfma_f32_16x16x32_f16(W1f[c], Bx[u], zero4, 0, 0, 0);
            unsigned w1w[2][8];
#pragma unroll
            for (int u = 0; u < 2; ++u) {
#pragma unroll
                for (int c = 0; c < 4; ++c) {
                    w1w[u][2 * c]     = swish2(a1[u][c].x, a1[u][c].y);
                    w1w[u][2 * c + 1] = swish2(a1[u][c].z, a1[u][c].w);
                }
                xpose64(w1w[u]);
            }
            half8 h1f[2][2];
#pragma unroll
            for (int u = 0; u < 2; ++u) {
                h1f[u][0] = mk8h(w1w[u][0], w1w[u][1], w1w[u][2], w1w[u][3]);
                h1f[u][1] = mk8h(w1w[u][4], w1w[u][5], w1w[u][6], w1w[u][7]);
            }

            // ---- layer 2 (64 -> 64)
            f32x4 a2[2][4];
#pragma unroll
            for (int u = 0; u < 2; ++u)
#pragma unroll
                for (int c = 0; c < 4; ++c) {
                    f32x4 t0 = __builtin_amdgcn_mfma_f32_16x16x32_f16(W2f[c][0], h1f[u][0], B2b[c], 0, 0, 0);
                    a2[u][c] = __builtin_amdgcn_mfma_f32_16x16x32_f16(W2f[c][1], h1f[u][1], t0, 0, 0, 0);
                }
            unsigned w2w[2][8];
#pragma unroll
            for (int u = 0; u < 2; ++u) {
#pragma unroll
                for (int c = 0; c < 4; ++c) {
                    w2w[u][2 * c]     = swish2(a2[u][c].x, a2[u][c].y);
                    w2w[u][2 * c + 1] = swish2(a2[u][c].z, a2[u][c].w);
                }
                xpose64(w2w[u]);
            }
            half8 h2f[2][2];
#pragma unroll
            for (int u = 0; u < 2; ++u) {
                h2f[u][0] = mk8h(w2w[u][0], w2w[u][1], w2w[u][2], w2w[u][3]);
                h2f[u][1] = mk8h(w2w[u][4], w2w[u][5], w2w[u][6], w2w[u][7]);
            }

            // ---- layer 3 (64 -> 32)
            f32x4 a3[2][2];
#pragma unroll
            for (int u = 0; u < 2; ++u)
#pragma unroll
                for (int c = 0; c < 2; ++c) {
                    f32x4 t0 = __builtin_amdgcn_mfma_f32_16x16x32_f16(W3f[c][0], h2f[u][0], B3b[c], 0, 0, 0);
                    a3[u][c] = __builtin_amdgcn_mfma_f32_16x16x32_f16(W3f[c][1], h2f[u][1], t0, 0, 0, 0);
                }
            unsigned w3w[2][4];
#pragma unroll
            for (int u = 0; u < 2; ++u) {
#pragma unroll
                for (int c = 0; c < 2; ++c) {
                    w3w[u][2 * c]     = swish2(a3[u][c].x, a3[u][c].y);
                    w3w[u][2 * c + 1] = swish2(a3[u][c].z, a3[u][c].w);
                }
                xpose32(w3w[u]);
            }

            // ---- layer 4 (32 -> 8, true domain) + Euler update (fp32)
#pragma unroll
            for (int u = 0; u < 2; ++u) {
                half8 h3f = mk8h(w3w[u][0], w3w[u][1], w3w[u][2], w3w[u][3]);
                f32x4 a4 = __builtin_amdgcn_mfma_f32_16x16x32_f16(W4f, h3f, B4b, 0, 0, 0);
                stD[u].x = fmaf(DT, a4.x, stD[u].x);
                stD[u].y = fmaf(DT, a4.y, stD[u].y);
                stD[u].z = fmaf(DT, a4.z, stD[u].z);
                stD[u].w = fmaf(DT, a4.w, stD[u].w);
            }
        }

        if (hi < 2) {
            *(f32x4*)(out + (size_t)rows[0] * 8 + 4 * hi) = stD[0];
            *(f32x4*)(out + (size_t)rows[1] * 8 + 4 * hi) = stD[1];
        }
    }
}

extern "C" void kernel_launch(void* const* d_in, const int* in_sizes, int n_in,
                              void* d_out, int out_size, void* d_ws, size_t ws_size,
                              hipStream_t stream) {
    const float* eta = (const float*)d_in[0];
    const float* W1  = (const float*)d_in[1];
    const float* b1  = (const float*)d_in[2];
    const float* W2  = (const float*)d_in[3];
    const float* b2  = (const float*)d_in[4];
    const float* W3  = (const float*)d_in[5];
    const float* b3  = (const float*)d_in[6];
    const float* W4  = (const float*)d_in[7];
    const float* b4  = (const float*)d_in[8];
    float* out = (float*)d_out;

    const int batch = in_sizes[0] / 8;
    const int block = 256;   // 4 waves
    const int grid  = 2048;  // 8192 waves -> 8 pairs (16 tiles) per wave
    hipLaunchKernelGGL(noprop_mfma_kernel, dim3(grid), dim3(block), 0, stream,
                       eta, W1, b1, W2, b2, W3, b3, W4, b4, out, batch);
}

// Round 10
// 875.996 us; speedup vs baseline: 1.1464x; 1.1273x over previous
//
#include <hip/hip_runtime.h>
#include <hip/hip_fp16.h>

// NoPropCTMomentNet: 10-step Euler of a 17->64->64->32->8 swish MLP, B=2M rows.
// Round 10 (= R8 + type fixes): minimal-cycle swish.
// swish_scaled(z) = max(z,0) + |z|*e*r(e), e = 2^-|z| (native v_exp_f32 on the
// f32 MFMA output, abs/neg modifiers free), r(e) = -1/(1+e) ~ deg-2 poly
// (exact at e=0 so saturated activations are exact).
// One 16-row tile per wave; in-register permlane transposes; t & b1 folded
// into W1; no LDS, no barriers.

typedef __attribute__((ext_vector_type(8))) _Float16 half8;
typedef __attribute__((ext_vector_type(2))) _Float16 h2f;
typedef __attribute__((ext_vector_type(4))) float f32x4;

constexpr int NSTEP = 10;
constexpr float DT = 0.1f;
constexpr float LOG2E = 1.44269504f;
constexpr float LN2   = 0.69314718f;

#if __has_builtin(__builtin_amdgcn_exp2f)
#define EXP2F(x) __builtin_amdgcn_exp2f(x)
#else
#define EXP2F(x) exp2f(x)
#endif

__device__ __forceinline__ unsigned packh(float a, float b) {
    __half2 h = __floats2half2_rn(a, b);
    unsigned r; __builtin_memcpy(&r, &h, 4); return r;
}
__device__ __forceinline__ unsigned pkrtz(float a, float b) {
    auto z = __builtin_amdgcn_cvt_pkrtz(a, b);
    unsigned r; __builtin_memcpy(&r, &z, 4); return r;
}
__device__ __forceinline__ h2f pkrtz_h(float a, float b) {
    auto z = __builtin_amdgcn_cvt_pkrtz(a, b);   // __fp16 ext_vector(2)
    h2f r; __builtin_memcpy(&r, &z, 4); return r;
}
__device__ __forceinline__ half8 mk8h(unsigned w0, unsigned w1,
                                      unsigned w2, unsigned w3) {
    union { unsigned w[4]; half8 h; } u;
    u.w[0] = w0; u.w[1] = w1; u.w[2] = w2; u.w[3] = w3;
    return u.h;
}

__device__ __forceinline__ void plswap32(unsigned& a, unsigned& b) {
    auto r = __builtin_amdgcn_permlane32_swap(a, b, false, false);
    a = r[0]; b = r[1];
}
__device__ __forceinline__ void plswap16(unsigned& a, unsigned& b) {
    auto r = __builtin_amdgcn_permlane16_swap(a, b, false, false);
    a = r[0]; b = r[1];
}
__device__ __forceinline__ unsigned partner16(unsigned x) {
    unsigned a = x, b = x;
    plswap16(a, b);
    return b;
}

// swish in scaled domain, 2 activations -> packed half2 word.
// hh = max(z,0) + |z| * e * r(e);  e = 2^-|z|;  r(e) = -1/(1+e) deg-2:
// r ~ -0.9903978 + 0.8141289 e - 0.3292181 e^2 (exact at e->0).
__device__ __forceinline__ unsigned swish2(float za, float zb) {
    const float ea = EXP2F(-__builtin_fabsf(za));   // v_exp_f32, mods folded
    const float eb = EXP2F(-__builtin_fabsf(zb));
    h2f z = pkrtz_h(za, zb);
    h2f e = pkrtz_h(ea, eb);
    h2f az = __builtin_elementwise_abs(z);
    h2f relu = __builtin_elementwise_max(z, (h2f)(_Float16)0);   // v_pk_max_f16
    const h2f C0 = (h2f)(_Float16)(-0.9903978f);
    const h2f C1 = (h2f)(_Float16)( 0.8141289f);
    const h2f C2 = (h2f)(_Float16)(-0.3292181f);
    h2f s = az * e;
    h2f r = (C2 * e + C1) * e + C0;
    h2f hh = s * r + relu;
    unsigned out; __builtin_memcpy(&out, &hh, 4);
    return out;
}

__device__ __forceinline__ void xpose64(unsigned w[8]) {
    plswap32(w[0], w[2]); plswap32(w[1], w[3]);
    plswap32(w[4], w[6]); plswap32(w[5], w[7]);
    plswap16(w[0], w[2]); plswap16(w[1], w[3]);
    plswap16(w[4], w[6]); plswap16(w[5], w[7]);
}
__device__ __forceinline__ void xpose32(unsigned w[4]) {
    plswap32(w[0], w[2]); plswap32(w[1], w[3]);
    plswap16(w[0], w[2]); plswap16(w[1], w[3]);
}

template <int NOUT, int KLIM, bool M8>
__device__ __forceinline__ half8 wfragh(const float* __restrict__ W, float scale,
                                        int c, int s, int n, int hi) {
    unsigned w[4];
#pragma unroll
    for (int p = 0; p < 4; ++p) {
        const int k0 = 32 * s + 8 * hi + 2 * p;
        const bool mok = !M8 || (n < 8);
        float a = (mok && (k0     < KLIM)) ? W[(size_t)k0 * NOUT + 16 * c + n] * scale : 0.0f;
        float b = (mok && (k0 + 1 < KLIM)) ? W[(size_t)(k0 + 1) * NOUT + 16 * c + n] * scale : 0.0f;
        w[p] = packh(a, b);
    }
    return mk8h(w[0], w[1], w[2], w[3]);
}

// W1 fragment with t-coeff at k=16 and bias at k=17 (virtual rows), scaled.
__device__ __forceinline__ half8 w1fragh(const float* __restrict__ W1,
                                         const float* __restrict__ b1,
                                         int c, int n, int hi) {
    unsigned w[4];
#pragma unroll
    for (int p = 0; p < 4; ++p) {
        const int k0 = 8 * hi + 2 * p;
        float a = (k0 < 17) ? W1[(size_t)k0 * 64 + 16 * c + n] * LOG2E
                            : (k0 == 17 ? b1[16 * c + n] * LOG2E : 0.0f);
        const int k1 = k0 + 1;
        float b = (k1 < 17) ? W1[(size_t)k1 * 64 + 16 * c + n] * LOG2E
                            : (k1 == 17 ? b1[16 * c + n] * LOG2E : 0.0f);
        w[p] = packh(a, b);
    }
    return mk8h(w[0], w[1], w[2], w[3]);
}

__device__ __forceinline__ f32x4 ldb4s(const float* p, float s) {
    f32x4 v = *(const f32x4*)p;
    v.x *= s; v.y *= s; v.z *= s; v.w *= s;
    return v;
}

__global__ __launch_bounds__(256) void noprop_mfma_kernel(
    const float* __restrict__ eta,
    const float* __restrict__ W1, const float* __restrict__ b1,
    const float* __restrict__ W2, const float* __restrict__ b2,
    const float* __restrict__ W3, const float* __restrict__ b3,
    const float* __restrict__ W4, const float* __restrict__ b4,
    float* __restrict__ out, int batch)
{
    const int lane = threadIdx.x & 63;
    const int n  = lane & 15;
    const int hi = lane >> 4;

    // ---- persistent weight fragments (scaled domain)
    half8 W1f[4], W2f[4][2], W3f[2][2], W4f;
#pragma unroll
    for (int c = 0; c < 4; ++c) W1f[c] = w1fragh(W1, b1, c, n, hi);
#pragma unroll
    for (int c = 0; c < 4; ++c)
#pragma unroll
        for (int s = 0; s < 2; ++s) W2f[c][s] = wfragh<64, 64, false>(W2, 1.0f, c, s, n, hi);
#pragma unroll
    for (int c = 0; c < 2; ++c)
#pragma unroll
        for (int s = 0; s < 2; ++s) W3f[c][s] = wfragh<32, 64, false>(W3, 1.0f, c, s, n, hi);
    W4f = wfragh<8, 32, true>(W4, LN2, 0, 0, n, hi);

    f32x4 zero4 = {0.f, 0.f, 0.f, 0.f};
    f32x4 B2b[4], B3b[2], B4b;
#pragma unroll
    for (int c = 0; c < 4; ++c) B2b[c] = ldb4s(b2 + 16 * c + 4 * hi, LOG2E);
#pragma unroll
    for (int c = 0; c < 2; ++c) B3b[c] = ldb4s(b3 + 16 * c + 4 * hi, LOG2E);
    B4b = (hi < 2) ? *(const f32x4*)(b4 + 4 * hi) : zero4;

    const int nTiles = batch >> 4;
    const int gwave  = (int)((blockIdx.x * blockDim.x + threadIdx.x) >> 6);
    const int nWaves = (int)((gridDim.x * blockDim.x) >> 6);

    for (int tile = gwave; tile < nTiles; tile += nWaves) {
        const int row = (tile << 4) + n;
        const float* erow = eta + (size_t)row * 8;

        f32x4 e0 = *(const f32x4*)(erow);
        f32x4 e1 = *(const f32x4*)(erow + 4);

        f32x4 stD = zero4;
        if (hi == 0) stD = e0;
        if (hi == 1) stD = e1;

        const unsigned eP0 = pkrtz(e0.x, e0.y), eP1 = pkrtz(e0.z, e0.w);
        const unsigned eP2 = pkrtz(e1.x, e1.y), eP3 = pkrtz(e1.z, e1.w);

#pragma unroll 1
        for (int step = 0; step < NSTEP; ++step) {
            const float t = DT * (float)step;
            const unsigned tw = pkrtz(t, 1.0f);   // (t, 1) -> W1 rows 16,17

            const unsigned pa = pkrtz(stD.x, stD.y);
            const unsigned pb = pkrtz(stD.z, stD.w);
            const unsigned paP = partner16(pa);
            const unsigned pbP = partner16(pb);
            unsigned b0  = (hi == 0) ? pa  : (hi == 1) ? eP0 : (hi == 2) ? tw : 0u;
            unsigned b1w = (hi == 0) ? pb  : (hi == 1) ? eP1 : 0u;
            unsigned b2w = (hi == 0) ? paP : (hi == 1) ? eP2 : 0u;
            unsigned b3w = (hi == 0) ? pbP : (hi == 1) ? eP3 : 0u;
            half8 Bx = mk8h(b0, b1w, b2w, b3w);

            // ---- layer 1 (17(+t,+1) -> 64)
            f32x4 a1[4];
#pragma unroll
            for (int c = 0; c < 4; ++c)
                a1[c] = __builtin_amdgcn_mfma_f32_16x16x32_f16(W1f[c], Bx, zero4, 0, 0, 0);
            unsigned w1w[8];
#pragma unroll
            for (int c = 0; c < 4; ++c) {
                w1w[2 * c]     = swish2(a1[c].x, a1[c].y);
                w1w[2 * c + 1] = swish2(a1[c].z, a1[c].w);
            }
            xpose64(w1w);
            half8 h1f0 = mk8h(w1w[0], w1w[1], w1w[2], w1w[3]);
            half8 h1f1 = mk8h(w1w[4], w1w[5], w1w[6], w1w[7]);

            // ---- layer 2 (64 -> 64)
            f32x4 a2[4];
#pragma unroll
            for (int c = 0; c < 4; ++c) {
                f32x4 t0 = __builtin_amdgcn_mfma_f32_16x16x32_f16(W2f[c][0], h1f0, B2b[c], 0, 0, 0);
                a2[c]    = __builtin_amdgcn_mfma_f32_16x16x32_f16(W2f[c][1], h1f1, t0, 0, 0, 0);
            }
            unsigned w2w[8];
#pragma unroll
            for (int c = 0; c < 4; ++c) {
                w2w[2 * c]     = swish2(a2[c].x, a2[c].y);
                w2w[2 * c + 1] = swish2(a2[c].z, a2[c].w);
            }
            xpose64(w2w);
            half8 h2f0 = mk8h(w2w[0], w2w[1], w2w[2], w2w[3]);
            half8 h2f1 = mk8h(w2w[4], w2w[5], w2w[6], w2w[7]);

            // ---- layer 3 (64 -> 32)
            f32x4 a3[2];
#pragma unroll
            for (int c = 0; c < 2; ++c) {
                f32x4 t0 = __builtin_amdgcn_mfma_f32_16x16x32_f16(W3f[c][0], h2f0, B3b[c], 0, 0, 0);
                a3[c]    = __builtin_amdgcn_mfma_f32_16x16x32_f16(W3f[c][1], h2f1, t0, 0, 0, 0);
            }
            unsigned w3w[4];
#pragma unroll
            for (int c = 0; c < 2; ++c) {
                w3w[2 * c]     = swish2(a3[c].x, a3[c].y);
                w3w[2 * c + 1] = swish2(a3[c].z, a3[c].w);
            }
            xpose32(w3w);
            half8 h3f = mk8h(w3w[0], w3w[1], w3w[2], w3w[3]);

            // ---- layer 4 (32 -> 8, true domain) + Euler update (fp32)
            f32x4 a4 = __builtin_amdgcn_mfma_f32_16x16x32_f16(W4f, h3f, B4b, 0, 0, 0);
            stD.x = fmaf(DT, a4.x, stD.x);
            stD.y = fmaf(DT, a4.y, stD.y);
            stD.z = fmaf(DT, a4.z, stD.z);
            stD.w = fmaf(DT, a4.w, stD.w);
        }

        if (hi < 2) *(f32x4*)(out + (size_t)row * 8 + 4 * hi) = stD;
    }
}

extern "C" void kernel_launch(void* const* d_in, const int* in_sizes, int n_in,
                              void* d_out, int out_size, void* d_ws, size_t ws_size,
                              hipStream_t stream) {
    const float* eta = (const float*)d_in[0];
    const float* W1  = (const float*)d_in[1];
    const float* b1  = (const float*)d_in[2];
    const float* W2  = (const float*)d_in[3];
    const float* b2  = (const float*)d_in[4];
    const float* W3  = (const float*)d_in[5];
    const float* b3  = (const float*)d_in[6];
    const float* W4  = (const float*)d_in[7];
    const float* b4  = (const float*)d_in[8];
    float* out = (float*)d_out;

    const int batch = in_sizes[0] / 8;
    const int block = 256;   // 4 waves
    const int grid  = 2048;  // 8192 waves -> 16 tiles/wave
    hipLaunchKernelGGL(noprop_mfma_kernel, dim3(grid), dim3(block), 0, stream,
                       eta, W1, b1, W2, b2, W3, b3, W4, b4, out, batch);
}

// Round 11
// 794.033 us; speedup vs baseline: 1.2648x; 1.1032x over previous
//
#include <hip/hip_runtime.h>
#include <hip/hip_fp16.h>

// NoPropCTMomentNet: 10-step Euler of a 17->64->64->32->8 swish MLP, B=2M rows.
// Round 11 = R10 + __launch_bounds__(256, 2).
// Theory: without the min-waves hint the compiler capped at the 128-VGPR
// occupancy tier (VGPR_Count=108 < ~145 live) and rematerialized the 17
// weight fragments (global_load + pack) EVERY step (~400 hidden VALU
// instrs/step). Raising the cap to 256 keeps them live across the loop.

typedef __attribute__((ext_vector_type(8))) _Float16 half8;
typedef __attribute__((ext_vector_type(2))) _Float16 h2f;
typedef __attribute__((ext_vector_type(4))) float f32x4;

constexpr int NSTEP = 10;
constexpr float DT = 0.1f;
constexpr float LOG2E = 1.44269504f;
constexpr float LN2   = 0.69314718f;

#if __has_builtin(__builtin_amdgcn_exp2f)
#define EXP2F(x) __builtin_amdgcn_exp2f(x)
#else
#define EXP2F(x) exp2f(x)
#endif

__device__ __forceinline__ unsigned packh(float a, float b) {
    __half2 h = __floats2half2_rn(a, b);
    unsigned r; __builtin_memcpy(&r, &h, 4); return r;
}
__device__ __forceinline__ unsigned pkrtz(float a, float b) {
    auto z = __builtin_amdgcn_cvt_pkrtz(a, b);
    unsigned r; __builtin_memcpy(&r, &z, 4); return r;
}
__device__ __forceinline__ h2f pkrtz_h(float a, float b) {
    auto z = __builtin_amdgcn_cvt_pkrtz(a, b);   // __fp16 ext_vector(2)
    h2f r; __builtin_memcpy(&r, &z, 4); return r;
}
__device__ __forceinline__ half8 mk8h(unsigned w0, unsigned w1,
                                      unsigned w2, unsigned w3) {
    union { unsigned w[4]; half8 h; } u;
    u.w[0] = w0; u.w[1] = w1; u.w[2] = w2; u.w[3] = w3;
    return u.h;
}

__device__ __forceinline__ void plswap32(unsigned& a, unsigned& b) {
    auto r = __builtin_amdgcn_permlane32_swap(a, b, false, false);
    a = r[0]; b = r[1];
}
__device__ __forceinline__ void plswap16(unsigned& a, unsigned& b) {
    auto r = __builtin_amdgcn_permlane16_swap(a, b, false, false);
    a = r[0]; b = r[1];
}
__device__ __forceinline__ unsigned partner16(unsigned x) {
    unsigned a = x, b = x;
    plswap16(a, b);
    return b;
}

// swish in scaled domain, 2 activations -> packed half2 word.
// hh = max(z,0) + |z| * e * r(e);  e = 2^-|z|;  r(e) = -1/(1+e) deg-2:
// r ~ -0.9903978 + 0.8141289 e - 0.3292181 e^2 (exact at e->0).
__device__ __forceinline__ unsigned swish2(float za, float zb) {
    const float ea = EXP2F(-__builtin_fabsf(za));   // v_exp_f32, mods folded
    const float eb = EXP2F(-__builtin_fabsf(zb));
    h2f z = pkrtz_h(za, zb);
    h2f e = pkrtz_h(ea, eb);
    h2f az = __builtin_elementwise_abs(z);
    h2f relu = __builtin_elementwise_max(z, (h2f)(_Float16)0);   // v_pk_max_f16
    const h2f C0 = (h2f)(_Float16)(-0.9903978f);
    const h2f C1 = (h2f)(_Float16)( 0.8141289f);
    const h2f C2 = (h2f)(_Float16)(-0.3292181f);
    h2f s = az * e;
    h2f r = (C2 * e + C1) * e + C0;
    h2f hh = s * r + relu;
    unsigned out; __builtin_memcpy(&out, &hh, 4);
    return out;
}

__device__ __forceinline__ void xpose64(unsigned w[8]) {
    plswap32(w[0], w[2]); plswap32(w[1], w[3]);
    plswap32(w[4], w[6]); plswap32(w[5], w[7]);
    plswap16(w[0], w[2]); plswap16(w[1], w[3]);
    plswap16(w[4], w[6]); plswap16(w[5], w[7]);
}
__device__ __forceinline__ void xpose32(unsigned w[4]) {
    plswap32(w[0], w[2]); plswap32(w[1], w[3]);
    plswap16(w[0], w[2]); plswap16(w[1], w[3]);
}

template <int NOUT, int KLIM, bool M8>
__device__ __forceinline__ half8 wfragh(const float* __restrict__ W, float scale,
                                        int c, int s, int n, int hi) {
    unsigned w[4];
#pragma unroll
    for (int p = 0; p < 4; ++p) {
        const int k0 = 32 * s + 8 * hi + 2 * p;
        const bool mok = !M8 || (n < 8);
        float a = (mok && (k0     < KLIM)) ? W[(size_t)k0 * NOUT + 16 * c + n] * scale : 0.0f;
        float b = (mok && (k0 + 1 < KLIM)) ? W[(size_t)(k0 + 1) * NOUT + 16 * c + n] * scale : 0.0f;
        w[p] = packh(a, b);
    }
    return mk8h(w[0], w[1], w[2], w[3]);
}

// W1 fragment with t-coeff at k=16 and bias at k=17 (virtual rows), scaled.
__device__ __forceinline__ half8 w1fragh(const float* __restrict__ W1,
                                         const float* __restrict__ b1,
                                         int c, int n, int hi) {
    unsigned w[4];
#pragma unroll
    for (int p = 0; p < 4; ++p) {
        const int k0 = 8 * hi + 2 * p;
        float a = (k0 < 17) ? W1[(size_t)k0 * 64 + 16 * c + n] * LOG2E
                            : (k0 == 17 ? b1[16 * c + n] * LOG2E : 0.0f);
        const int k1 = k0 + 1;
        float b = (k1 < 17) ? W1[(size_t)k1 * 64 + 16 * c + n] * LOG2E
                            : (k1 == 17 ? b1[16 * c + n] * LOG2E : 0.0f);
        w[p] = packh(a, b);
    }
    return mk8h(w[0], w[1], w[2], w[3]);
}

__device__ __forceinline__ f32x4 ldb4s(const float* p, float s) {
    f32x4 v = *(const f32x4*)p;
    v.x *= s; v.y *= s; v.z *= s; v.w *= s;
    return v;
}

__global__ __launch_bounds__(256, 2) void noprop_mfma_kernel(
    const float* __restrict__ eta,
    const float* __restrict__ W1, const float* __restrict__ b1,
    const float* __restrict__ W2, const float* __restrict__ b2,
    const float* __restrict__ W3, const float* __restrict__ b3,
    const float* __restrict__ W4, const float* __restrict__ b4,
    float* __restrict__ out, int batch)
{
    const int lane = threadIdx.x & 63;
    const int n  = lane & 15;
    const int hi = lane >> 4;

    // ---- persistent weight fragments (scaled domain)
    half8 W1f[4], W2f[4][2], W3f[2][2], W4f;
#pragma unroll
    for (int c = 0; c < 4; ++c) W1f[c] = w1fragh(W1, b1, c, n, hi);
#pragma unroll
    for (int c = 0; c < 4; ++c)
#pragma unroll
        for (int s = 0; s < 2; ++s) W2f[c][s] = wfragh<64, 64, false>(W2, 1.0f, c, s, n, hi);
#pragma unroll
    for (int c = 0; c < 2; ++c)
#pragma unroll
        for (int s = 0; s < 2; ++s) W3f[c][s] = wfragh<32, 64, false>(W3, 1.0f, c, s, n, hi);
    W4f = wfragh<8, 32, true>(W4, LN2, 0, 0, n, hi);

    f32x4 zero4 = {0.f, 0.f, 0.f, 0.f};
    f32x4 B2b[4], B3b[2], B4b;
#pragma unroll
    for (int c = 0; c < 4; ++c) B2b[c] = ldb4s(b2 + 16 * c + 4 * hi, LOG2E);
#pragma unroll
    for (int c = 0; c < 2; ++c) B3b[c] = ldb4s(b3 + 16 * c + 4 * hi, LOG2E);
    B4b = (hi < 2) ? *(const f32x4*)(b4 + 4 * hi) : zero4;

    const int nTiles = batch >> 4;
    const int gwave  = (int)((blockIdx.x * blockDim.x + threadIdx.x) >> 6);
    const int nWaves = (int)((gridDim.x * blockDim.x) >> 6);

    for (int tile = gwave; tile < nTiles; tile += nWaves) {
        const int row = (tile << 4) + n;
        const float* erow = eta + (size_t)row * 8;

        f32x4 e0 = *(const f32x4*)(erow);
        f32x4 e1 = *(const f32x4*)(erow + 4);

        f32x4 stD = zero4;
        if (hi == 0) stD = e0;
        if (hi == 1) stD = e1;

        const unsigned eP0 = pkrtz(e0.x, e0.y), eP1 = pkrtz(e0.z, e0.w);
        const unsigned eP2 = pkrtz(e1.x, e1.y), eP3 = pkrtz(e1.z, e1.w);

#pragma unroll 1
        for (int step = 0; step < NSTEP; ++step) {
            const float t = DT * (float)step;
            const unsigned tw = pkrtz(t, 1.0f);   // (t, 1) -> W1 rows 16,17

            const unsigned pa = pkrtz(stD.x, stD.y);
            const unsigned pb = pkrtz(stD.z, stD.w);
            const unsigned paP = partner16(pa);
            const unsigned pbP = partner16(pb);
            unsigned b0  = (hi == 0) ? pa  : (hi == 1) ? eP0 : (hi == 2) ? tw : 0u;
            unsigned b1w = (hi == 0) ? pb  : (hi == 1) ? eP1 : 0u;
            unsigned b2w = (hi == 0) ? paP : (hi == 1) ? eP2 : 0u;
            unsigned b3w = (hi == 0) ? pbP : (hi == 1) ? eP3 : 0u;
            half8 Bx = mk8h(b0, b1w, b2w, b3w);

            // ---- layer 1 (17(+t,+1) -> 64)
            f32x4 a1[4];
#pragma unroll
            for (int c = 0; c < 4; ++c)
                a1[c] = __builtin_amdgcn_mfma_f32_16x16x32_f16(W1f[c], Bx, zero4, 0, 0, 0);
            unsigned w1w[8];
#pragma unroll
            for (int c = 0; c < 4; ++c) {
                w1w[2 * c]     = swish2(a1[c].x, a1[c].y);
                w1w[2 * c + 1] = swish2(a1[c].z, a1[c].w);
            }
            xpose64(w1w);
            half8 h1f0 = mk8h(w1w[0], w1w[1], w1w[2], w1w[3]);
            half8 h1f1 = mk8h(w1w[4], w1w[5], w1w[6], w1w[7]);

            // ---- layer 2 (64 -> 64)
            f32x4 a2[4];
#pragma unroll
            for (int c = 0; c < 4; ++c) {
                f32x4 t0 = __builtin_amdgcn_mfma_f32_16x16x32_f16(W2f[c][0], h1f0, B2b[c], 0, 0, 0);
                a2[c]    = __builtin_amdgcn_mfma_f32_16x16x32_f16(W2f[c][1], h1f1, t0, 0, 0, 0);
            }
            unsigned w2w[8];
#pragma unroll
            for (int c = 0; c < 4; ++c) {
                w2w[2 * c]     = swish2(a2[c].x, a2[c].y);
                w2w[2 * c + 1] = swish2(a2[c].z, a2[c].w);
            }
            xpose64(w2w);
            half8 h2f0 = mk8h(w2w[0], w2w[1], w2w[2], w2w[3]);
            half8 h2f1 = mk8h(w2w[4], w2w[5], w2w[6], w2w[7]);

            // ---- layer 3 (64 -> 32)
            f32x4 a3[2];
#pragma unroll
            for (int c = 0; c < 2; ++c) {
                f32x4 t0 = __builtin_amdgcn_mfma_f32_16x16x32_f16(W3f[c][0], h2f0, B3b[c], 0, 0, 0);
                a3[c]    = __builtin_amdgcn_mfma_f32_16x16x32_f16(W3f[c][1], h2f1, t0, 0, 0, 0);
            }
            unsigned w3w[4];
#pragma unroll
            for (int c = 0; c < 2; ++c) {
                w3w[2 * c]     = swish2(a3[c].x, a3[c].y);
                w3w[2 * c + 1] = swish2(a3[c].z, a3[c].w);
            }
            xpose32(w3w);
            half8 h3f = mk8h(w3w[0], w3w[1], w3w[2], w3w[3]);

            // ---- layer 4 (32 -> 8, true domain) + Euler update (fp32)
            f32x4 a4 = __builtin_amdgcn_mfma_f32_16x16x32_f16(W4f, h3f, B4b, 0, 0, 0);
            stD.x = fmaf(DT, a4.x, stD.x);
            stD.y = fmaf(DT, a4.y, stD.y);
            stD.z = fmaf(DT, a4.z, stD.z);
            stD.w = fmaf(DT, a4.w, stD.w);
        }

        if (hi < 2) *(f32x4*)(out + (size_t)row * 8 + 4 * hi) = stD;
    }
}

extern "C" void kernel_launch(void* const* d_in, const int* in_sizes, int n_in,
                              void* d_out, int out_size, void* d_ws, size_t ws_size,
                              hipStream_t stream) {
    const float* eta = (const float*)d_in[0];
    const float* W1  = (const float*)d_in[1];
    const float* b1  = (const float*)d_in[2];
    const float* W2  = (const float*)d_in[3];
    const float* b2  = (const float*)d_in[4];
    const float* W3  = (const float*)d_in[5];
    const float* b3  = (const float*)d_in[6];
    const float* W4  = (const float*)d_in[7];
    const float* b4  = (const float*)d_in[8];
    float* out = (float*)d_out;

    const int batch = in_sizes[0] / 8;
    const int block = 256;   // 4 waves
    const int grid  = 2048;  // 8192 waves -> 16 tiles/wave
    hipLaunchKernelGGL(noprop_mfma_kernel, dim3(grid), dim3(block), 0, stream,
                       eta, W1, b1, W2, b2, W3, b3, W4, b4, out, batch);
}

// Round 12
// 790.547 us; speedup vs baseline: 1.2703x; 1.0044x over previous
//
#include <hip/hip_runtime.h>
#include <hip/hip_fp16.h>

// NoPropCTMomentNet: 10-step Euler of a 17->64->64->32->8 swish MLP, B=2M rows.
// Round 12 = R11 + asm-pinned weight/bias fragments.
// R11 proved the compiler REMATERIALIZES weight fragments every step (chose
// VGPR=88 with a 256 budget; ~1100 hidden VALU cyc/step re-loading+packing).
// Fix: redefine each fragment through an empty asm ("+v") after init — its
// origin becomes the asm, remat is impossible, fragments stay resident.

typedef __attribute__((ext_vector_type(8))) _Float16 half8;
typedef __attribute__((ext_vector_type(2))) _Float16 h2f;
typedef __attribute__((ext_vector_type(4))) float f32x4;

constexpr int NSTEP = 10;
constexpr float DT = 0.1f;
constexpr float LOG2E = 1.44269504f;
constexpr float LN2   = 0.69314718f;

#if __has_builtin(__builtin_amdgcn_exp2f)
#define EXP2F(x) __builtin_amdgcn_exp2f(x)
#else
#define EXP2F(x) exp2f(x)
#endif

__device__ __forceinline__ void keep8(half8& v) { asm volatile("" : "+v"(v)); }
__device__ __forceinline__ void keep4(f32x4& v) { asm volatile("" : "+v"(v)); }

__device__ __forceinline__ unsigned packh(float a, float b) {
    __half2 h = __floats2half2_rn(a, b);
    unsigned r; __builtin_memcpy(&r, &h, 4); return r;
}
__device__ __forceinline__ unsigned pkrtz(float a, float b) {
    auto z = __builtin_amdgcn_cvt_pkrtz(a, b);
    unsigned r; __builtin_memcpy(&r, &z, 4); return r;
}
__device__ __forceinline__ h2f pkrtz_h(float a, float b) {
    auto z = __builtin_amdgcn_cvt_pkrtz(a, b);   // __fp16 ext_vector(2)
    h2f r; __builtin_memcpy(&r, &z, 4); return r;
}
__device__ __forceinline__ half8 mk8h(unsigned w0, unsigned w1,
                                      unsigned w2, unsigned w3) {
    union { unsigned w[4]; half8 h; } u;
    u.w[0] = w0; u.w[1] = w1; u.w[2] = w2; u.w[3] = w3;
    return u.h;
}

__device__ __forceinline__ void plswap32(unsigned& a, unsigned& b) {
    auto r = __builtin_amdgcn_permlane32_swap(a, b, false, false);
    a = r[0]; b = r[1];
}
__device__ __forceinline__ void plswap16(unsigned& a, unsigned& b) {
    auto r = __builtin_amdgcn_permlane16_swap(a, b, false, false);
    a = r[0]; b = r[1];
}
__device__ __forceinline__ unsigned partner16(unsigned x) {
    unsigned a = x, b = x;
    plswap16(a, b);
    return b;
}

// swish in scaled domain, 2 activations -> packed half2 word.
// hh = max(z,0) + |z| * e * r(e);  e = 2^-|z|;  r(e) = -1/(1+e) deg-2:
// r ~ -0.9903978 + 0.8141289 e - 0.3292181 e^2 (exact at e->0).
__device__ __forceinline__ unsigned swish2(float za, float zb) {
    const float ea = EXP2F(-__builtin_fabsf(za));   // v_exp_f32, mods folded
    const float eb = EXP2F(-__builtin_fabsf(zb));
    h2f z = pkrtz_h(za, zb);
    h2f e = pkrtz_h(ea, eb);
    h2f az = __builtin_elementwise_abs(z);
    h2f relu = __builtin_elementwise_max(z, (h2f)(_Float16)0);   // v_pk_max_f16
    const h2f C0 = (h2f)(_Float16)(-0.9903978f);
    const h2f C1 = (h2f)(_Float16)( 0.8141289f);
    const h2f C2 = (h2f)(_Float16)(-0.3292181f);
    h2f s = az * e;
    h2f r = (C2 * e + C1) * e + C0;
    h2f hh = s * r + relu;
    unsigned out; __builtin_memcpy(&out, &hh, 4);
    return out;
}

__device__ __forceinline__ void xpose64(unsigned w[8]) {
    plswap32(w[0], w[2]); plswap32(w[1], w[3]);
    plswap32(w[4], w[6]); plswap32(w[5], w[7]);
    plswap16(w[0], w[2]); plswap16(w[1], w[3]);
    plswap16(w[4], w[6]); plswap16(w[5], w[7]);
}
__device__ __forceinline__ void xpose32(unsigned w[4]) {
    plswap32(w[0], w[2]); plswap32(w[1], w[3]);
    plswap16(w[0], w[2]); plswap16(w[1], w[3]);
}

template <int NOUT, int KLIM, bool M8>
__device__ __forceinline__ half8 wfragh(const float* __restrict__ W, float scale,
                                        int c, int s, int n, int hi) {
    unsigned w[4];
#pragma unroll
    for (int p = 0; p < 4; ++p) {
        const int k0 = 32 * s + 8 * hi + 2 * p;
        const bool mok = !M8 || (n < 8);
        float a = (mok && (k0     < KLIM)) ? W[(size_t)k0 * NOUT + 16 * c + n] * scale : 0.0f;
        float b = (mok && (k0 + 1 < KLIM)) ? W[(size_t)(k0 + 1) * NOUT + 16 * c + n] * scale : 0.0f;
        w[p] = packh(a, b);
    }
    return mk8h(w[0], w[1], w[2], w[3]);
}

// W1 fragment with t-coeff at k=16 and bias at k=17 (virtual rows), scaled.
__device__ __forceinline__ half8 w1fragh(const float* __restrict__ W1,
                                         const float* __restrict__ b1,
                                         int c, int n, int hi) {
    unsigned w[4];
#pragma unroll
    for (int p = 0; p < 4; ++p) {
        const int k0 = 8 * hi + 2 * p;
        float a = (k0 < 17) ? W1[(size_t)k0 * 64 + 16 * c + n] * LOG2E
                            : (k0 == 17 ? b1[16 * c + n] * LOG2E : 0.0f);
        const int k1 = k0 + 1;
        float b = (k1 < 17) ? W1[(size_t)k1 * 64 + 16 * c + n] * LOG2E
                            : (k1 == 17 ? b1[16 * c + n] * LOG2E : 0.0f);
        w[p] = packh(a, b);
    }
    return mk8h(w[0], w[1], w[2], w[3]);
}

__device__ __forceinline__ f32x4 ldb4s(const float* p, float s) {
    f32x4 v = *(const f32x4*)p;
    v.x *= s; v.y *= s; v.z *= s; v.w *= s;
    return v;
}

__global__ __launch_bounds__(256, 2) void noprop_mfma_kernel(
    const float* __restrict__ eta,
    const float* __restrict__ W1, const float* __restrict__ b1,
    const float* __restrict__ W2, const float* __restrict__ b2,
    const float* __restrict__ W3, const float* __restrict__ b3,
    const float* __restrict__ W4, const float* __restrict__ b4,
    float* __restrict__ out, int batch)
{
    const int lane = threadIdx.x & 63;
    const int n  = lane & 15;
    const int hi = lane >> 4;

    // ---- persistent weight fragments (scaled domain), PINNED in registers
    half8 W1f[4], W2f[4][2], W3f[2][2], W4f;
#pragma unroll
    for (int c = 0; c < 4; ++c) W1f[c] = w1fragh(W1, b1, c, n, hi);
#pragma unroll
    for (int c = 0; c < 4; ++c)
#pragma unroll
        for (int s = 0; s < 2; ++s) W2f[c][s] = wfragh<64, 64, false>(W2, 1.0f, c, s, n, hi);
#pragma unroll
    for (int c = 0; c < 2; ++c)
#pragma unroll
        for (int s = 0; s < 2; ++s) W3f[c][s] = wfragh<32, 64, false>(W3, 1.0f, c, s, n, hi);
    W4f = wfragh<8, 32, true>(W4, LN2, 0, 0, n, hi);

    f32x4 zero4 = {0.f, 0.f, 0.f, 0.f};
    f32x4 B2b[4], B3b[2], B4b;
#pragma unroll
    for (int c = 0; c < 4; ++c) B2b[c] = ldb4s(b2 + 16 * c + 4 * hi, LOG2E);
#pragma unroll
    for (int c = 0; c < 2; ++c) B3b[c] = ldb4s(b3 + 16 * c + 4 * hi, LOG2E);
    B4b = (hi < 2) ? *(const f32x4*)(b4 + 4 * hi) : zero4;

    // pin: origins become the asm -> rematerialization impossible
#pragma unroll
    for (int c = 0; c < 4; ++c) keep8(W1f[c]);
#pragma unroll
    for (int c = 0; c < 4; ++c) { keep8(W2f[c][0]); keep8(W2f[c][1]); }
#pragma unroll
    for (int c = 0; c < 2; ++c) { keep8(W3f[c][0]); keep8(W3f[c][1]); }
    keep8(W4f);
#pragma unroll
    for (int c = 0; c < 4; ++c) keep4(B2b[c]);
#pragma unroll
    for (int c = 0; c < 2; ++c) keep4(B3b[c]);
    keep4(B4b);

    const int nTiles = batch >> 4;
    const int gwave  = (int)((blockIdx.x * blockDim.x + threadIdx.x) >> 6);
    const int nWaves = (int)((gridDim.x * blockDim.x) >> 6);

    for (int tile = gwave; tile < nTiles; tile += nWaves) {
        const int row = (tile << 4) + n;
        const float* erow = eta + (size_t)row * 8;

        f32x4 e0 = *(const f32x4*)(erow);
        f32x4 e1 = *(const f32x4*)(erow + 4);

        f32x4 stD = zero4;
        if (hi == 0) stD = e0;
        if (hi == 1) stD = e1;

        const unsigned eP0 = pkrtz(e0.x, e0.y), eP1 = pkrtz(e0.z, e0.w);
        const unsigned eP2 = pkrtz(e1.x, e1.y), eP3 = pkrtz(e1.z, e1.w);

#pragma unroll 1
        for (int step = 0; step < NSTEP; ++step) {
            const float t = DT * (float)step;
            const unsigned tw = pkrtz(t, 1.0f);   // (t, 1) -> W1 rows 16,17

            const unsigned pa = pkrtz(stD.x, stD.y);
            const unsigned pb = pkrtz(stD.z, stD.w);
            const unsigned paP = partner16(pa);
            const unsigned pbP = partner16(pb);
            unsigned b0  = (hi == 0) ? pa  : (hi == 1) ? eP0 : (hi == 2) ? tw : 0u;
            unsigned b1w = (hi == 0) ? pb  : (hi == 1) ? eP1 : 0u;
            unsigned b2w = (hi == 0) ? paP : (hi == 1) ? eP2 : 0u;
            unsigned b3w = (hi == 0) ? pbP : (hi == 1) ? eP3 : 0u;
            half8 Bx = mk8h(b0, b1w, b2w, b3w);

            // ---- layer 1 (17(+t,+1) -> 64)
            f32x4 a1[4];
#pragma unroll
            for (int c = 0; c < 4; ++c)
                a1[c] = __builtin_amdgcn_mfma_f32_16x16x32_f16(W1f[c], Bx, zero4, 0, 0, 0);
            unsigned w1w[8];
#pragma unroll
            for (int c = 0; c < 4; ++c) {
                w1w[2 * c]     = swish2(a1[c].x, a1[c].y);
                w1w[2 * c + 1] = swish2(a1[c].z, a1[c].w);
            }
            xpose64(w1w);
            half8 h1f0 = mk8h(w1w[0], w1w[1], w1w[2], w1w[3]);
            half8 h1f1 = mk8h(w1w[4], w1w[5], w1w[6], w1w[7]);

            // ---- layer 2 (64 -> 64)
            f32x4 a2[4];
#pragma unroll
            for (int c = 0; c < 4; ++c) {
                f32x4 t0 = __builtin_amdgcn_mfma_f32_16x16x32_f16(W2f[c][0], h1f0, B2b[c], 0, 0, 0);
                a2[c]    = __builtin_amdgcn_mfma_f32_16x16x32_f16(W2f[c][1], h1f1, t0, 0, 0, 0);
            }
            unsigned w2w[8];
#pragma unroll
            for (int c = 0; c < 4; ++c) {
                w2w[2 * c]     = swish2(a2[c].x, a2[c].y);
                w2w[2 * c + 1] = swish2(a2[c].z, a2[c].w);
            }
            xpose64(w2w);
            half8 h2f0 = mk8h(w2w[0], w2w[1], w2w[2], w2w[3]);
            half8 h2f1 = mk8h(w2w[4], w2w[5], w2w[6], w2w[7]);

            // ---- layer 3 (64 -> 32)
            f32x4 a3[2];
#pragma unroll
            for (int c = 0; c < 2; ++c) {
                f32x4 t0 = __builtin_amdgcn_mfma_f32_16x16x32_f16(W3f[c][0], h2f0, B3b[c], 0, 0, 0);
                a3[c]    = __builtin_amdgcn_mfma_f32_16x16x32_f16(W3f[c][1], h2f1, t0, 0, 0, 0);
            }
            unsigned w3w[4];
#pragma unroll
            for (int c = 0; c < 2; ++c) {
                w3w[2 * c]     = swish2(a3[c].x, a3[c].y);
                w3w[2 * c + 1] = swish2(a3[c].z, a3[c].w);
            }
            xpose32(w3w);
            half8 h3f = mk8h(w3w[0], w3w[1], w3w[2], w3w[3]);

            // ---- layer 4 (32 -> 8, true domain) + Euler update (fp32)
            f32x4 a4 = __builtin_amdgcn_mfma_f32_16x16x32_f16(W4f, h3f, B4b, 0, 0, 0);
            stD.x = fmaf(DT, a4.x, stD.x);
            stD.y = fmaf(DT, a4.y, stD.y);
            stD.z = fmaf(DT, a4.z, stD.z);
            stD.w = fmaf(DT, a4.w, stD.w);
        }

        if (hi < 2) *(f32x4*)(out + (size_t)row * 8 + 4 * hi) = stD;
    }
}

extern "C" void kernel_launch(void* const* d_in, const int* in_sizes, int n_in,
                              void* d_out, int out_size, void* d_ws, size_t ws_size,
                              hipStream_t stream) {
    const float* eta = (const float*)d_in[0];
    const float* W1  = (const float*)d_in[1];
    const float* b1  = (const float*)d_in[2];
    const float* W2  = (const float*)d_in[3];
    const float* b2  = (const float*)d_in[4];
    const float* W3  = (const float*)d_in[5];
    const float* b3  = (const float*)d_in[6];
    const float* W4  = (const float*)d_in[7];
    const float* b4  = (const float*)d_in[8];
    float* out = (float*)d_out;

    const int batch = in_sizes[0] / 8;
    const int block = 256;   // 4 waves
    const int grid  = 2048;  // 8192 waves -> 16 tiles/wave
    hipLaunchKernelGGL(noprop_mfma_kernel, dim3(grid), dim3(block), 0, stream,
                       eta, W1, b1, W2, b2, W3, b3, W4, b4, out, batch);
}

// Round 13
// 772.867 us; speedup vs baseline: 1.2994x; 1.0229x over previous
//
#include <hip/hip_runtime.h>
#include <hip/hip_fp16.h>

// NoPropCTMomentNet: 10-step Euler of a 17->64->64->32->8 swish MLP, B=2M rows.
// Round 13: weight fragments live in LDS (built once by wave 0, one sync),
// read per step with ds_read_b128 (lane-contiguous 16B = canonical full-BW,
// conflict-free). Removes the compiler's freedom to rebuild fragments from
// global memory every step (R11/R12 showed source-level register hints can't
// control this). Everything else identical to R10/R11.

typedef __attribute__((ext_vector_type(8))) _Float16 half8;
typedef __attribute__((ext_vector_type(2))) _Float16 h2f;
typedef __attribute__((ext_vector_type(4))) float f32x4;

constexpr int NSTEP = 10;
constexpr float DT = 0.1f;
constexpr float LOG2E = 1.44269504f;
constexpr float LN2   = 0.69314718f;

#if __has_builtin(__builtin_amdgcn_exp2f)
#define EXP2F(x) __builtin_amdgcn_exp2f(x)
#else
#define EXP2F(x) exp2f(x)
#endif

__device__ __forceinline__ unsigned packh(float a, float b) {
    __half2 h = __floats2half2_rn(a, b);
    unsigned r; __builtin_memcpy(&r, &h, 4); return r;
}
__device__ __forceinline__ unsigned pkrtz(float a, float b) {
    auto z = __builtin_amdgcn_cvt_pkrtz(a, b);
    unsigned r; __builtin_memcpy(&r, &z, 4); return r;
}
__device__ __forceinline__ h2f pkrtz_h(float a, float b) {
    auto z = __builtin_amdgcn_cvt_pkrtz(a, b);   // __fp16 ext_vector(2)
    h2f r; __builtin_memcpy(&r, &z, 4); return r;
}
__device__ __forceinline__ half8 mk8h(unsigned w0, unsigned w1,
                                      unsigned w2, unsigned w3) {
    union { unsigned w[4]; half8 h; } u;
    u.w[0] = w0; u.w[1] = w1; u.w[2] = w2; u.w[3] = w3;
    return u.h;
}

__device__ __forceinline__ void plswap32(unsigned& a, unsigned& b) {
    auto r = __builtin_amdgcn_permlane32_swap(a, b, false, false);
    a = r[0]; b = r[1];
}
__device__ __forceinline__ void plswap16(unsigned& a, unsigned& b) {
    auto r = __builtin_amdgcn_permlane16_swap(a, b, false, false);
    a = r[0]; b = r[1];
}
__device__ __forceinline__ unsigned partner16(unsigned x) {
    unsigned a = x, b = x;
    plswap16(a, b);
    return b;
}

// swish in scaled domain, 2 activations -> packed half2 word.
// hh = max(z,0) + |z| * e * r(e);  e = 2^-|z|;  r(e) = -1/(1+e) deg-2:
// r ~ -0.9903978 + 0.8141289 e - 0.3292181 e^2 (exact at e->0).
__device__ __forceinline__ unsigned swish2(float za, float zb) {
    const float ea = EXP2F(-__builtin_fabsf(za));   // v_exp_f32, mods folded
    const float eb = EXP2F(-__builtin_fabsf(zb));
    h2f z = pkrtz_h(za, zb);
    h2f e = pkrtz_h(ea, eb);
    h2f az = __builtin_elementwise_abs(z);
    h2f relu = __builtin_elementwise_max(z, (h2f)(_Float16)0);   // v_pk_max_f16
    const h2f C0 = (h2f)(_Float16)(-0.9903978f);
    const h2f C1 = (h2f)(_Float16)( 0.8141289f);
    const h2f C2 = (h2f)(_Float16)(-0.3292181f);
    h2f s = az * e;
    h2f r = (C2 * e + C1) * e + C0;
    h2f hh = s * r + relu;
    unsigned out; __builtin_memcpy(&out, &hh, 4);
    return out;
}

__device__ __forceinline__ void xpose64(unsigned w[8]) {
    plswap32(w[0], w[2]); plswap32(w[1], w[3]);
    plswap32(w[4], w[6]); plswap32(w[5], w[7]);
    plswap16(w[0], w[2]); plswap16(w[1], w[3]);
    plswap16(w[4], w[6]); plswap16(w[5], w[7]);
}
__device__ __forceinline__ void xpose32(unsigned w[4]) {
    plswap32(w[0], w[2]); plswap32(w[1], w[3]);
    plswap16(w[0], w[2]); plswap16(w[1], w[3]);
}

template <int NOUT, int KLIM, bool M8>
__device__ __forceinline__ half8 wfragh(const float* __restrict__ W, float scale,
                                        int c, int s, int n, int hi) {
    unsigned w[4];
#pragma unroll
    for (int p = 0; p < 4; ++p) {
        const int k0 = 32 * s + 8 * hi + 2 * p;
        const bool mok = !M8 || (n < 8);
        float a = (mok && (k0     < KLIM)) ? W[(size_t)k0 * NOUT + 16 * c + n] * scale : 0.0f;
        float b = (mok && (k0 + 1 < KLIM)) ? W[(size_t)(k0 + 1) * NOUT + 16 * c + n] * scale : 0.0f;
        w[p] = packh(a, b);
    }
    return mk8h(w[0], w[1], w[2], w[3]);
}

// W1 fragment with t-coeff at k=16 and bias at k=17 (virtual rows), scaled.
__device__ __forceinline__ half8 w1fragh(const float* __restrict__ W1,
                                         const float* __restrict__ b1,
                                         int c, int n, int hi) {
    unsigned w[4];
#pragma unroll
    for (int p = 0; p < 4; ++p) {
        const int k0 = 8 * hi + 2 * p;
        float a = (k0 < 17) ? W1[(size_t)k0 * 64 + 16 * c + n] * LOG2E
                            : (k0 == 17 ? b1[16 * c + n] * LOG2E : 0.0f);
        const int k1 = k0 + 1;
        float b = (k1 < 17) ? W1[(size_t)k1 * 64 + 16 * c + n] * LOG2E
                            : (k1 == 17 ? b1[16 * c + n] * LOG2E : 0.0f);
        w[p] = packh(a, b);
    }
    return mk8h(w[0], w[1], w[2], w[3]);
}

__device__ __forceinline__ f32x4 ldb4s(const float* p, float s) {
    f32x4 v = *(const f32x4*)p;
    v.x *= s; v.y *= s; v.z *= s; v.w *= s;
    return v;
}

__global__ __launch_bounds__(256, 2) void noprop_mfma_kernel(
    const float* __restrict__ eta,
    const float* __restrict__ W1, const float* __restrict__ b1,
    const float* __restrict__ W2, const float* __restrict__ b2,
    const float* __restrict__ W3, const float* __restrict__ b3,
    const float* __restrict__ W4, const float* __restrict__ b4,
    float* __restrict__ out, int batch)
{
    const int lane = threadIdx.x & 63;
    const int n  = lane & 15;
    const int hi = lane >> 4;

    // ---- weight fragments in LDS: [frag 0..16][lane 0..63], 16B each.
    // f = 0..3: W1 chunk c | 4..11: W2 (c*2+s) | 12..15: W3 (c*2+s) | 16: W4
    __shared__ half8 wlds[17 * 64];
    if (threadIdx.x < 64) {
#pragma unroll
        for (int c = 0; c < 4; ++c)
            wlds[c * 64 + lane] = w1fragh(W1, b1, c, n, hi);
#pragma unroll
        for (int c = 0; c < 4; ++c)
#pragma unroll
            for (int s = 0; s < 2; ++s)
                wlds[(4 + 2 * c + s) * 64 + lane] = wfragh<64, 64, false>(W2, 1.0f, c, s, n, hi);
#pragma unroll
        for (int c = 0; c < 2; ++c)
#pragma unroll
            for (int s = 0; s < 2; ++s)
                wlds[(12 + 2 * c + s) * 64 + lane] = wfragh<32, 64, false>(W3, 1.0f, c, s, n, hi);
        wlds[16 * 64 + lane] = wfragh<8, 32, true>(W4, LN2, 0, 0, n, hi);
    }

    f32x4 zero4 = {0.f, 0.f, 0.f, 0.f};
    f32x4 B2b[4], B3b[2], B4b;
#pragma unroll
    for (int c = 0; c < 4; ++c) B2b[c] = ldb4s(b2 + 16 * c + 4 * hi, LOG2E);
#pragma unroll
    for (int c = 0; c < 2; ++c) B3b[c] = ldb4s(b3 + 16 * c + 4 * hi, LOG2E);
    B4b = (hi < 2) ? *(const f32x4*)(b4 + 4 * hi) : zero4;

    __syncthreads();   // once; weights are read-only afterwards

    const int nTiles = batch >> 4;
    const int gwave  = (int)((blockIdx.x * blockDim.x + threadIdx.x) >> 6);
    const int nWaves = (int)((gridDim.x * blockDim.x) >> 6);

    for (int tile = gwave; tile < nTiles; tile += nWaves) {
        const int row = (tile << 4) + n;
        const float* erow = eta + (size_t)row * 8;

        f32x4 e0 = *(const f32x4*)(erow);
        f32x4 e1 = *(const f32x4*)(erow + 4);

        f32x4 stD = zero4;
        if (hi == 0) stD = e0;
        if (hi == 1) stD = e1;

        const unsigned eP0 = pkrtz(e0.x, e0.y), eP1 = pkrtz(e0.z, e0.w);
        const unsigned eP2 = pkrtz(e1.x, e1.y), eP3 = pkrtz(e1.z, e1.w);

#pragma unroll 1
        for (int step = 0; step < NSTEP; ++step) {
            const float t = DT * (float)step;
            const unsigned tw = pkrtz(t, 1.0f);   // (t, 1) -> W1 rows 16,17

            const unsigned pa = pkrtz(stD.x, stD.y);
            const unsigned pb = pkrtz(stD.z, stD.w);
            const unsigned paP = partner16(pa);
            const unsigned pbP = partner16(pb);
            unsigned b0  = (hi == 0) ? pa  : (hi == 1) ? eP0 : (hi == 2) ? tw : 0u;
            unsigned b1w = (hi == 0) ? pb  : (hi == 1) ? eP1 : 0u;
            unsigned b2w = (hi == 0) ? paP : (hi == 1) ? eP2 : 0u;
            unsigned b3w = (hi == 0) ? pbP : (hi == 1) ? eP3 : 0u;
            half8 Bx = mk8h(b0, b1w, b2w, b3w);

            // ---- layer 1 (17(+t,+1) -> 64)
            f32x4 a1[4];
#pragma unroll
            for (int c = 0; c < 4; ++c)
                a1[c] = __builtin_amdgcn_mfma_f32_16x16x32_f16(wlds[c * 64 + lane], Bx, zero4, 0, 0, 0);
            unsigned w1w[8];
#pragma unroll
            for (int c = 0; c < 4; ++c) {
                w1w[2 * c]     = swish2(a1[c].x, a1[c].y);
                w1w[2 * c + 1] = swish2(a1[c].z, a1[c].w);
            }
            xpose64(w1w);
            half8 h1f0 = mk8h(w1w[0], w1w[1], w1w[2], w1w[3]);
            half8 h1f1 = mk8h(w1w[4], w1w[5], w1w[6], w1w[7]);

            // ---- layer 2 (64 -> 64)
            f32x4 a2[4];
#pragma unroll
            for (int c = 0; c < 4; ++c) {
                f32x4 t0 = __builtin_amdgcn_mfma_f32_16x16x32_f16(wlds[(4 + 2 * c) * 64 + lane], h1f0, B2b[c], 0, 0, 0);
                a2[c]    = __builtin_amdgcn_mfma_f32_16x16x32_f16(wlds[(5 + 2 * c) * 64 + lane], h1f1, t0, 0, 0, 0);
            }
            unsigned w2w[8];
#pragma unroll
            for (int c = 0; c < 4; ++c) {
                w2w[2 * c]     = swish2(a2[c].x, a2[c].y);
                w2w[2 * c + 1] = swish2(a2[c].z, a2[c].w);
            }
            xpose64(w2w);
            half8 h2f0 = mk8h(w2w[0], w2w[1], w2w[2], w2w[3]);
            half8 h2f1 = mk8h(w2w[4], w2w[5], w2w[6], w2w[7]);

            // ---- layer 3 (64 -> 32)
            f32x4 a3[2];
#pragma unroll
            for (int c = 0; c < 2; ++c) {
                f32x4 t0 = __builtin_amdgcn_mfma_f32_16x16x32_f16(wlds[(12 + 2 * c) * 64 + lane], h2f0, B3b[c], 0, 0, 0);
                a3[c]    = __builtin_amdgcn_mfma_f32_16x16x32_f16(wlds[(13 + 2 * c) * 64 + lane], h2f1, t0, 0, 0, 0);
            }
            unsigned w3w[4];
#pragma unroll
            for (int c = 0; c < 2; ++c) {
                w3w[2 * c]     = swish2(a3[c].x, a3[c].y);
                w3w[2 * c + 1] = swish2(a3[c].z, a3[c].w);
            }
            xpose32(w3w);
            half8 h3f = mk8h(w3w[0], w3w[1], w3w[2], w3w[3]);

            // ---- layer 4 (32 -> 8, true domain) + Euler update (fp32)
            f32x4 a4 = __builtin_amdgcn_mfma_f32_16x16x32_f16(wlds[16 * 64 + lane], h3f, B4b, 0, 0, 0);
            stD.x = fmaf(DT, a4.x, stD.x);
            stD.y = fmaf(DT, a4.y, stD.y);
            stD.z = fmaf(DT, a4.z, stD.z);
            stD.w = fmaf(DT, a4.w, stD.w);
        }

        if (hi < 2) *(f32x4*)(out + (size_t)row * 8 + 4 * hi) = stD;
    }
}

extern "C" void kernel_launch(void* const* d_in, const int* in_sizes, int n_in,
                              void* d_out, int out_size, void* d_ws, size_t ws_size,
                              hipStream_t stream) {
    const float* eta = (const float*)d_in[0];
    const float* W1  = (const float*)d_in[1];
    const float* b1  = (const float*)d_in[2];
    const float* W2  = (const float*)d_in[3];
    const float* b2  = (const float*)d_in[4];
    const float* W3  = (const float*)d_in[5];
    const float* b3  = (const float*)d_in[6];
    const float* W4  = (const float*)d_in[7];
    const float* b4  = (const float*)d_in[8];
    float* out = (float*)d_out;

    const int batch = in_sizes[0] / 8;
    const int block = 256;   // 4 waves
    const int grid  = 2048;  // 8192 waves -> 16 tiles/wave
    hipLaunchKernelGGL(noprop_mfma_kernel, dim3(grid), dim3(block), 0, stream,
                       eta, W1, b1, W2, b2, W3, b3, W4, b4, out, batch);
}